// Round 2
// baseline (3120.916 us; speedup 1.0000x reference)
//
#include <hip/hip_runtime.h>
#include <math.h>

constexpr float EPS_BN = 1e-5f;
constexpr float SLOPE = 0.2f;

__device__ __forceinline__ unsigned fenc(float f) {
    unsigned b = __float_as_uint(f);
    return (b & 0x80000000u) ? ~b : (b | 0x80000000u);
}
__device__ __forceinline__ float fdec(unsigned k) {
    unsigned b = (k & 0x80000000u) ? (k ^ 0x80000000u) : ~k;
    return __uint_as_float(b);
}

// ---------------- column stats (+ optional bias add with writeback) -------------
// grid: (nblocks), block: (C) threads. stats[0..C)=sum, stats[C..2C)=sumsq
__global__ void col_stats_kernel(float* __restrict__ data, const float* __restrict__ bias,
                                 float* __restrict__ stats, int n, int c) {
    int f = threadIdx.x;
    float bv = bias ? bias[f] : 0.0f;
    float s = 0.0f, q = 0.0f;
    for (int r = blockIdx.x; r < n; r += gridDim.x) {
        float v = data[(size_t)r * c + f] + bv;
        if (bias) data[(size_t)r * c + f] = v;
        s += v;
        q += v * v;
    }
    atomicAdd(&stats[f], s);
    atomicAdd(&stats[c + f], q);
}

// ---------------- BN apply (input) -------------------------------------------
__global__ void bn_apply_kernel(const float4* __restrict__ x, const float* __restrict__ stats,
                                const float* __restrict__ g, const float* __restrict__ b,
                                float4* __restrict__ h, int n, int c) {
    int c4 = c / 4;
    int i = blockIdx.x * blockDim.x + threadIdx.x;
    if (i >= n * c4) return;
    int f = (i % c4) * 4;
    float4 v = x[i];
    float4 o;
    float invn = 1.0f / (float)n;
#pragma unroll
    for (int j = 0; j < 4; j++) {
        float mean = stats[f + j] * invn;
        float var = stats[c + f + j] * invn - mean * mean;
        float rs = rsqrtf(var + EPS_BN);
        float xv = (&v.x)[j];
        (&o.x)[j] = g[f + j] * (xv - mean) * rs + b[f + j];
    }
    h[i] = o;
}

// ---------------- BN + ELU + residual ----------------------------------------
__global__ void bn_elu_res_kernel(const float4* __restrict__ out, const float* __restrict__ stats,
                                  const float* __restrict__ g, const float* __restrict__ b,
                                  const float4* __restrict__ res, float4* __restrict__ dst,
                                  int n, int c) {
    int c4 = c / 4;
    int i = blockIdx.x * blockDim.x + threadIdx.x;
    if (i >= n * c4) return;
    int f = (i % c4) * 4;
    float4 v = out[i];
    float4 r = res[i];
    float4 o;
    float invn = 1.0f / (float)n;
#pragma unroll
    for (int j = 0; j < 4; j++) {
        float mean = stats[f + j] * invn;
        float var = stats[c + f + j] * invn - mean * mean;
        float rs = rsqrtf(var + EPS_BN);
        float y = g[f + j] * ((&v.x)[j] - mean) * rs + b[f + j];
        float e = (y > 0.0f) ? y : expm1f(y);
        (&o.x)[j] = e + (&r.x)[j];
    }
    dst[i] = o;
}

// ---------------- GEMM: Y[n x m] = X[n x 128] @ W[128 x m] + bias -------------
// block tile 64x64, thread tile 4x4, 256 threads
__device__ __forceinline__ void fma4(float4& a, float s, const float4& w) {
    a.x += s * w.x; a.y += s * w.y; a.z += s * w.z; a.w += s * w.w;
}

__global__ __launch_bounds__(256) void gemm_bias_kernel(
        const float* __restrict__ X, const float* __restrict__ W,
        const float* __restrict__ bias, float* __restrict__ Y, int n, int m) {
    constexpr int KD = 128;
    __shared__ float sX[64 * KD];
    __shared__ float sW[KD * 64];
    int t = threadIdx.x;
    int col0 = blockIdx.x * 64;
    int row0 = blockIdx.y * 64;

    // load X tile: 64 rows x 128 cols = 2048 float4
    const float4* X4 = (const float4*)X;
    float4* sX4 = (float4*)sX;
    for (int i = t; i < 2048; i += 256) {
        int r = i >> 5;          // 32 float4 per row
        int k4 = i & 31;
        int gr = row0 + r;
        float4 v = make_float4(0.f, 0.f, 0.f, 0.f);
        if (gr < n) v = X4[(size_t)gr * 32 + k4];
        sX4[i] = v;
    }
    // load W tile: 128 rows x 64 cols = 2048 float4
    float4* sW4 = (float4*)sW;
    for (int i = t; i < 2048; i += 256) {
        int k = i >> 4;          // 16 float4 per row
        int c4 = i & 15;
        sW4[i] = *(const float4*)&W[(size_t)k * m + col0 + c4 * 4];
    }
    __syncthreads();

    int ty = t >> 4, tx = t & 15;
    int r0 = ty * 4;
    float4 acc0 = make_float4(0.f, 0.f, 0.f, 0.f);
    float4 acc1 = acc0, acc2 = acc0, acc3 = acc0;

#pragma unroll 8
    for (int k4 = 0; k4 < 32; k4++) {
        float4 xv0 = sX4[(r0 + 0) * 32 + k4];
        float4 xv1 = sX4[(r0 + 1) * 32 + k4];
        float4 xv2 = sX4[(r0 + 2) * 32 + k4];
        float4 xv3 = sX4[(r0 + 3) * 32 + k4];
        float4 w0 = sW4[(k4 * 4 + 0) * 16 + tx];
        float4 w1 = sW4[(k4 * 4 + 1) * 16 + tx];
        float4 w2 = sW4[(k4 * 4 + 2) * 16 + tx];
        float4 w3 = sW4[(k4 * 4 + 3) * 16 + tx];
        fma4(acc0, xv0.x, w0); fma4(acc0, xv0.y, w1); fma4(acc0, xv0.z, w2); fma4(acc0, xv0.w, w3);
        fma4(acc1, xv1.x, w0); fma4(acc1, xv1.y, w1); fma4(acc1, xv1.z, w2); fma4(acc1, xv1.w, w3);
        fma4(acc2, xv2.x, w0); fma4(acc2, xv2.y, w1); fma4(acc2, xv2.z, w2); fma4(acc2, xv2.w, w3);
        fma4(acc3, xv3.x, w0); fma4(acc3, xv3.y, w1); fma4(acc3, xv3.z, w2); fma4(acc3, xv3.w, w3);
    }

    int gc = col0 + tx * 4;
    float4 bv = *(const float4*)&bias[gc];
    float4* Y4 = (float4*)Y;
    int m4 = m / 4;
#pragma unroll
    for (int r = 0; r < 4; r++) {
        int gr = row0 + r0 + r;
        if (gr < n) {
            float4 a = (r == 0) ? acc0 : (r == 1) ? acc1 : (r == 2) ? acc2 : acc3;
            a.x += bv.x; a.y += bv.y; a.z += bv.z; a.w += bv.w;
            Y4[(size_t)gr * m4 + (gc >> 2)] = a;
        }
    }
}

// ---------------- edge scores + segment max -----------------------------------
template <int H, int C, int VPL>
__global__ void edge_score_kernel(const float* __restrict__ xl, const float* __restrict__ xr,
                                  const float* __restrict__ att, const int* __restrict__ ei,
                                  int E, int Etot, float* __restrict__ score,
                                  unsigned* __restrict__ smax) {
    int gt = blockIdx.x * blockDim.x + threadIdx.x;
    int e = gt >> 6;
    int lane = gt & 63;
    if (e >= Etot) return;
    int src, dst;
    if (e < E) { src = ei[e]; dst = ei[E + e]; }
    else       { src = dst = e - E; }
    constexpr int HC = H * C;
    float s;
    if (VPL == 2) {
        int base = lane * 2;
        float2 a = *(const float2*)&xl[(size_t)src * HC + base];
        float2 b = *(const float2*)&xr[(size_t)dst * HC + base];
        float2 av = *(const float2*)&att[base];
        float u = a.x + b.x; u = (u >= 0.f) ? u : SLOPE * u;
        float v = a.y + b.y; v = (v >= 0.f) ? v : SLOPE * v;
        s = u * av.x + v * av.y;
    } else {
        int base = lane;
        float u = xl[(size_t)src * HC + base] + xr[(size_t)dst * HC + base];
        u = (u >= 0.f) ? u : SLOPE * u;
        s = u * att[base];
    }
    constexpr int LPH = C / VPL;  // lanes per head
#pragma unroll
    for (int off = 1; off < LPH; off <<= 1) s += __shfl_xor(s, off, 64);
    if ((lane & (LPH - 1)) == 0) {
        int head = lane / LPH;
        score[(size_t)e * H + head] = s;
        atomicMax(&smax[(size_t)dst * H + head], fenc(s));
    }
}

// ---------------- p = exp(score - max); denom += p ----------------------------
template <int H>
__global__ void edge_p_kernel(float* __restrict__ score, const unsigned* __restrict__ smax,
                              float* __restrict__ denom, const int* __restrict__ ei,
                              int E, int Etot) {
    int e = blockIdx.x * blockDim.x + threadIdx.x;
    if (e >= Etot) return;
    int dst = (e < E) ? ei[E + e] : e - E;
#pragma unroll
    for (int h = 0; h < H; h++) {
        float m = fdec(smax[(size_t)dst * H + h]);
        float p = __expf(score[(size_t)e * H + h] - m);
        score[(size_t)e * H + h] = p;
        atomicAdd(&denom[(size_t)dst * H + h], p);
    }
}

// ---------------- message scatter: out[dst] += xl[src] * alpha ----------------
template <int H, int C, int VPL>
__global__ void edge_msg_kernel(const float* __restrict__ xl, const float* __restrict__ score,
                                const float* __restrict__ denom, const int* __restrict__ ei,
                                int E, int Etot, float* __restrict__ out) {
    int gt = blockIdx.x * blockDim.x + threadIdx.x;
    int e = gt >> 6;
    int lane = gt & 63;
    if (e >= Etot) return;
    int src, dst;
    if (e < E) { src = ei[e]; dst = ei[E + e]; }
    else       { src = dst = e - E; }
    constexpr int HC = H * C;
    if (VPL == 2) {
        int base = lane * 2;
        int head = base / C;
        float alpha = score[(size_t)e * H + head] / denom[(size_t)dst * H + head];
        float2 a = *(const float2*)&xl[(size_t)src * HC + base];
        atomicAdd(&out[(size_t)dst * HC + base], a.x * alpha);
        atomicAdd(&out[(size_t)dst * HC + base + 1], a.y * alpha);
    } else {
        int base = lane;
        float alpha = score[e] / denom[dst];
        atomicAdd(&out[(size_t)dst * HC + base], xl[(size_t)src * HC + base] * alpha);
    }
}

// ---------------- fused classifier: relu(v@W1+b1)@W2+b2 ----------------------
__global__ __launch_bounds__(256) void classifier_kernel(
        const float* __restrict__ out2, const float* __restrict__ bias2,
        const float* __restrict__ W1, const float* __restrict__ b1,
        const float* __restrict__ W2, const float* __restrict__ b2,
        float* __restrict__ y, int n) {
    __shared__ float sW1[64 * 32];
    __shared__ float sW2[32 * 64];
    __shared__ float sb1[32], sb2[64], sbias2[64];
    int t = threadIdx.x;
    for (int i = t; i < 2048; i += 256) { sW1[i] = W1[i]; sW2[i] = W2[i]; }
    if (t < 32) sb1[t] = b1[t];
    if (t < 64) { sb2[t] = b2[t]; sbias2[t] = bias2[t]; }
    __syncthreads();
    int node = blockIdx.x * blockDim.x + t;
    if (node >= n) return;
    float v[64];
    const float4* src4 = (const float4*)&out2[(size_t)node * 64];
#pragma unroll
    for (int i = 0; i < 16; i++) {
        float4 f = src4[i];
        v[4 * i + 0] = f.x + sbias2[4 * i + 0];
        v[4 * i + 1] = f.y + sbias2[4 * i + 1];
        v[4 * i + 2] = f.z + sbias2[4 * i + 2];
        v[4 * i + 3] = f.w + sbias2[4 * i + 3];
    }
    float hid[32];
#pragma unroll
    for (int j = 0; j < 32; j++) {
        float s = sb1[j];
#pragma unroll
        for (int i = 0; i < 64; i++) s += v[i] * sW1[i * 32 + j];
        hid[j] = fmaxf(s, 0.0f);
    }
    float4* y4 = (float4*)&y[(size_t)node * 64];
#pragma unroll
    for (int o4 = 0; o4 < 16; o4++) {
        float4 o;
#pragma unroll
        for (int j = 0; j < 4; j++) {
            int o_ = o4 * 4 + j;
            float s = sb2[o_];
#pragma unroll
            for (int k = 0; k < 32; k++) s += hid[k] * sW2[k * 64 + o_];
            (&o.x)[j] = s;
        }
        y4[o4] = o;
    }
}

// =============================================================================
extern "C" void kernel_launch(void* const* d_in, const int* in_sizes, int n_in,
                              void* d_out, int out_size, void* d_ws, size_t ws_size,
                              hipStream_t stream) {
    const float* x        = (const float*)d_in[0];
    const int*   ei       = (const int*)d_in[1];
    const float* bn_in_g  = (const float*)d_in[2];
    const float* bn_in_b  = (const float*)d_in[3];
    const float* c0_Wl    = (const float*)d_in[4];
    const float* c0_bl    = (const float*)d_in[5];
    const float* c0_Wr    = (const float*)d_in[6];
    const float* c0_br    = (const float*)d_in[7];
    const float* c0_att   = (const float*)d_in[8];
    const float* c0_bias  = (const float*)d_in[9];
    const float* bn0_g    = (const float*)d_in[10];
    const float* bn0_b    = (const float*)d_in[11];
    const float* c1_Wl    = (const float*)d_in[12];
    const float* c1_bl    = (const float*)d_in[13];
    const float* c1_Wr    = (const float*)d_in[14];
    const float* c1_br    = (const float*)d_in[15];
    const float* c1_att   = (const float*)d_in[16];
    const float* c1_bias  = (const float*)d_in[17];
    const float* bn1_g    = (const float*)d_in[18];
    const float* bn1_b    = (const float*)d_in[19];
    const float* c2_Wl    = (const float*)d_in[20];
    const float* c2_bl    = (const float*)d_in[21];
    const float* c2_Wr    = (const float*)d_in[22];
    const float* c2_br    = (const float*)d_in[23];
    const float* c2_att   = (const float*)d_in[24];
    const float* c2_bias  = (const float*)d_in[25];
    const float* cls_w1   = (const float*)d_in[26];
    const float* cls_b1   = (const float*)d_in[27];
    const float* cls_w2   = (const float*)d_in[28];
    const float* cls_b2   = (const float*)d_in[29];

    const int N = in_sizes[0] / 128;
    const int E = in_sizes[1] / 2;
    const int Et = E + N;

    float* ws = (float*)d_ws;
    size_t off = 0;
    auto alloc = [&](size_t nf) { float* p = ws + off; off += nf; return p; };
    float*    hA     = alloc((size_t)N * 128);
    float*    xlb    = alloc((size_t)N * 128);
    float*    xrb    = alloc((size_t)N * 128);
    float*    outb   = alloc((size_t)N * 128);
    float*    scoreb = alloc((size_t)Et * 4);
    unsigned* smax   = (unsigned*)alloc((size_t)N * 4);
    float*    denom  = alloc((size_t)N * 4);
    float*    stats  = alloc(256);

    const int ew_blocks = (Et * 64 + 255) / 256;   // wave-per-edge kernels
    const int ep_blocks = (Et + 255) / 256;
    const int elem128   = (N * 32 + 255) / 256;    // N*128/4 threads
    dim3 gemm_grid_128(2, (N + 63) / 64);
    dim3 gemm_grid_64(1, (N + 63) / 64);

    // ---- input BN ----
    hipMemsetAsync(stats, 0, 256 * sizeof(float), stream);
    col_stats_kernel<<<512, 128, 0, stream>>>(const_cast<float*>(x), nullptr, stats, N, 128);
    bn_apply_kernel<<<elem128, 256, 0, stream>>>((const float4*)x, stats, bn_in_g, bn_in_b,
                                                 (float4*)hA, N, 128);

    float* h = hA;

    // ================= layer 0 =================
    gemm_bias_kernel<<<gemm_grid_128, 256, 0, stream>>>(h, c0_Wl, c0_bl, xlb, N, 128);
    gemm_bias_kernel<<<gemm_grid_128, 256, 0, stream>>>(h, c0_Wr, c0_br, xrb, N, 128);
    hipMemsetAsync(smax, 0, (size_t)N * 4 * sizeof(unsigned), stream);
    hipMemsetAsync(denom, 0, (size_t)N * 4 * sizeof(float), stream);
    hipMemsetAsync(outb, 0, (size_t)N * 128 * sizeof(float), stream);
    edge_score_kernel<4, 32, 2><<<ew_blocks, 256, 0, stream>>>(xlb, xrb, c0_att, ei, E, Et, scoreb, smax);
    edge_p_kernel<4><<<ep_blocks, 256, 0, stream>>>(scoreb, smax, denom, ei, E, Et);
    edge_msg_kernel<4, 32, 2><<<ew_blocks, 256, 0, stream>>>(xlb, scoreb, denom, ei, E, Et, outb);
    hipMemsetAsync(stats, 0, 256 * sizeof(float), stream);
    col_stats_kernel<<<512, 128, 0, stream>>>(outb, c0_bias, stats, N, 128);
    // h_next -> xrb (free after scores); res = h
    bn_elu_res_kernel<<<elem128, 256, 0, stream>>>((const float4*)outb, stats, bn0_g, bn0_b,
                                                   (const float4*)h, (float4*)xrb, N, 128);
    h = xrb;  // hA now free

    // ================= layer 1 =================
    gemm_bias_kernel<<<gemm_grid_128, 256, 0, stream>>>(h, c1_Wl, c1_bl, xlb, N, 128);
    gemm_bias_kernel<<<gemm_grid_128, 256, 0, stream>>>(h, c1_Wr, c1_br, hA, N, 128);
    hipMemsetAsync(smax, 0, (size_t)N * 4 * sizeof(unsigned), stream);
    hipMemsetAsync(denom, 0, (size_t)N * 4 * sizeof(float), stream);
    hipMemsetAsync(outb, 0, (size_t)N * 128 * sizeof(float), stream);
    edge_score_kernel<4, 32, 2><<<ew_blocks, 256, 0, stream>>>(xlb, hA, c1_att, ei, E, Et, scoreb, smax);
    edge_p_kernel<4><<<ep_blocks, 256, 0, stream>>>(scoreb, smax, denom, ei, E, Et);
    edge_msg_kernel<4, 32, 2><<<ew_blocks, 256, 0, stream>>>(xlb, scoreb, denom, ei, E, Et, outb);
    hipMemsetAsync(stats, 0, 256 * sizeof(float), stream);
    col_stats_kernel<<<512, 128, 0, stream>>>(outb, c1_bias, stats, N, 128);
    // h_next -> hA (free after scores); res = h (= xrb)
    bn_elu_res_kernel<<<elem128, 256, 0, stream>>>((const float4*)outb, stats, bn1_g, bn1_b,
                                                   (const float4*)h, (float4*)hA, N, 128);
    h = hA;

    // ================= layer 2 (H=1, C=64) =================
    gemm_bias_kernel<<<gemm_grid_64, 256, 0, stream>>>(h, c2_Wl, c2_bl, xlb, N, 64);
    gemm_bias_kernel<<<gemm_grid_64, 256, 0, stream>>>(h, c2_Wr, c2_br, xrb, N, 64);
    hipMemsetAsync(smax, 0, (size_t)N * sizeof(unsigned), stream);
    hipMemsetAsync(denom, 0, (size_t)N * sizeof(float), stream);
    hipMemsetAsync(outb, 0, (size_t)N * 64 * sizeof(float), stream);
    edge_score_kernel<1, 64, 1><<<ew_blocks, 256, 0, stream>>>(xlb, xrb, c2_att, ei, E, Et, scoreb, smax);
    edge_p_kernel<1><<<ep_blocks, 256, 0, stream>>>(scoreb, smax, denom, ei, E, Et);
    edge_msg_kernel<1, 64, 1><<<ew_blocks, 256, 0, stream>>>(xlb, scoreb, denom, ei, E, Et, outb);

    // ---- classifier (fuses conv2 bias) ----
    classifier_kernel<<<(N + 255) / 256, 256, 0, stream>>>(outb, c2_bias, cls_w1, cls_b1,
                                                           cls_w2, cls_b2, (float*)d_out, N);
}

// Round 3
// 1010.807 us; speedup vs baseline: 3.0876x; 3.0876x over previous
//
#include <hip/hip_runtime.h>
#include <math.h>

constexpr float EPS_BN = 1e-5f;
constexpr float SLOPE = 0.2f;

// ---------------- column stats (+ optional bias add with writeback) -------------
__global__ void col_stats_kernel(float* __restrict__ data, const float* __restrict__ bias,
                                 float* __restrict__ stats, int n, int c) {
    int f = threadIdx.x;
    float bv = bias ? bias[f] : 0.0f;
    float s = 0.0f, q = 0.0f;
    for (int r = blockIdx.x; r < n; r += gridDim.x) {
        float v = data[(size_t)r * c + f] + bv;
        if (bias) data[(size_t)r * c + f] = v;
        s += v;
        q += v * v;
    }
    atomicAdd(&stats[f], s);
    atomicAdd(&stats[c + f], q);
}

// ---------------- BN apply (input) -------------------------------------------
__global__ void bn_apply_kernel(const float4* __restrict__ x, const float* __restrict__ stats,
                                const float* __restrict__ g, const float* __restrict__ b,
                                float4* __restrict__ h, int n, int c) {
    int c4 = c / 4;
    int i = blockIdx.x * blockDim.x + threadIdx.x;
    if (i >= n * c4) return;
    int f = (i % c4) * 4;
    float4 v = x[i];
    float4 o;
    float invn = 1.0f / (float)n;
#pragma unroll
    for (int j = 0; j < 4; j++) {
        float mean = stats[f + j] * invn;
        float var = stats[c + f + j] * invn - mean * mean;
        float rs = rsqrtf(var + EPS_BN);
        float xv = (&v.x)[j];
        (&o.x)[j] = g[f + j] * (xv - mean) * rs + b[f + j];
    }
    h[i] = o;
}

// ---------------- BN + ELU + residual ----------------------------------------
__global__ void bn_elu_res_kernel(const float4* __restrict__ out, const float* __restrict__ stats,
                                  const float* __restrict__ g, const float* __restrict__ b,
                                  const float4* __restrict__ res, float4* __restrict__ dst,
                                  int n, int c) {
    int c4 = c / 4;
    int i = blockIdx.x * blockDim.x + threadIdx.x;
    if (i >= n * c4) return;
    int f = (i % c4) * 4;
    float4 v = out[i];
    float4 r = res[i];
    float4 o;
    float invn = 1.0f / (float)n;
#pragma unroll
    for (int j = 0; j < 4; j++) {
        float mean = stats[f + j] * invn;
        float var = stats[c + f + j] * invn - mean * mean;
        float rs = rsqrtf(var + EPS_BN);
        float y = g[f + j] * ((&v.x)[j] - mean) * rs + b[f + j];
        float e = (y > 0.0f) ? y : expm1f(y);
        (&o.x)[j] = e + (&r.x)[j];
    }
    dst[i] = o;
}

// ---------------- GEMM: Y[n x m] = X[n x 128] @ W[128 x m] + bias -------------
__device__ __forceinline__ void fma4(float4& a, float s, const float4& w) {
    a.x += s * w.x; a.y += s * w.y; a.z += s * w.z; a.w += s * w.w;
}

__global__ __launch_bounds__(256) void gemm_bias_kernel(
        const float* __restrict__ X, const float* __restrict__ W,
        const float* __restrict__ bias, float* __restrict__ Y, int n, int m) {
    constexpr int KD = 128;
    __shared__ float sX[64 * KD];
    __shared__ float sW[KD * 64];
    int t = threadIdx.x;
    int col0 = blockIdx.x * 64;
    int row0 = blockIdx.y * 64;

    const float4* X4 = (const float4*)X;
    float4* sX4 = (float4*)sX;
    for (int i = t; i < 2048; i += 256) {
        int r = i >> 5;
        int k4 = i & 31;
        int gr = row0 + r;
        float4 v = make_float4(0.f, 0.f, 0.f, 0.f);
        if (gr < n) v = X4[(size_t)gr * 32 + k4];
        sX4[i] = v;
    }
    float4* sW4 = (float4*)sW;
    for (int i = t; i < 2048; i += 256) {
        int k = i >> 4;
        int c4 = i & 15;
        sW4[i] = *(const float4*)&W[(size_t)k * m + col0 + c4 * 4];
    }
    __syncthreads();

    int ty = t >> 4, tx = t & 15;
    int r0 = ty * 4;
    float4 acc0 = make_float4(0.f, 0.f, 0.f, 0.f);
    float4 acc1 = acc0, acc2 = acc0, acc3 = acc0;

#pragma unroll 8
    for (int k4 = 0; k4 < 32; k4++) {
        float4 xv0 = sX4[(r0 + 0) * 32 + k4];
        float4 xv1 = sX4[(r0 + 1) * 32 + k4];
        float4 xv2 = sX4[(r0 + 2) * 32 + k4];
        float4 xv3 = sX4[(r0 + 3) * 32 + k4];
        float4 w0 = sW4[(k4 * 4 + 0) * 16 + tx];
        float4 w1 = sW4[(k4 * 4 + 1) * 16 + tx];
        float4 w2 = sW4[(k4 * 4 + 2) * 16 + tx];
        float4 w3 = sW4[(k4 * 4 + 3) * 16 + tx];
        fma4(acc0, xv0.x, w0); fma4(acc0, xv0.y, w1); fma4(acc0, xv0.z, w2); fma4(acc0, xv0.w, w3);
        fma4(acc1, xv1.x, w0); fma4(acc1, xv1.y, w1); fma4(acc1, xv1.z, w2); fma4(acc1, xv1.w, w3);
        fma4(acc2, xv2.x, w0); fma4(acc2, xv2.y, w1); fma4(acc2, xv2.z, w2); fma4(acc2, xv2.w, w3);
        fma4(acc3, xv3.x, w0); fma4(acc3, xv3.y, w1); fma4(acc3, xv3.z, w2); fma4(acc3, xv3.w, w3);
    }

    int gc = col0 + tx * 4;
    float4 bv = *(const float4*)&bias[gc];
    float4* Y4 = (float4*)Y;
    int m4 = m / 4;
#pragma unroll
    for (int r = 0; r < 4; r++) {
        int gr = row0 + r0 + r;
        if (gr < n) {
            float4 a = (r == 0) ? acc0 : (r == 1) ? acc1 : (r == 2) ? acc2 : acc3;
            a.x += bv.x; a.y += bv.y; a.z += bv.z; a.w += bv.w;
            Y4[(size_t)gr * m4 + (gc >> 2)] = a;
        }
    }
}

// ================= CSR build (graph identical for all 3 layers) ===============
__global__ void degree_kernel(const int* __restrict__ ei, int E, int Et, int* __restrict__ deg) {
    int e = blockIdx.x * blockDim.x + threadIdx.x;
    if (e >= Et) return;
    int dst = (e < E) ? ei[E + e] : e - E;
    atomicAdd(&deg[dst], 1);
}

__global__ void blocksum_kernel(const int* __restrict__ deg, int n, int* __restrict__ bsum) {
    __shared__ int sd[256];
    int i = blockIdx.x * 256 + threadIdx.x;
    sd[threadIdx.x] = (i < n) ? deg[i] : 0;
    __syncthreads();
    for (int s = 128; s > 0; s >>= 1) {
        if (threadIdx.x < s) sd[threadIdx.x] += sd[threadIdx.x + s];
        __syncthreads();
    }
    if (threadIdx.x == 0) bsum[blockIdx.x] = sd[0];
}

// single block: exclusive scan of bsum[0..nb) in place
__global__ void scanb_kernel(int* __restrict__ bsum, int nb) {
    __shared__ int sd[256];
    int tid = threadIdx.x;
    int v = (tid < nb) ? bsum[tid] : 0;
    sd[tid] = v;
    __syncthreads();
    for (int off = 1; off < 256; off <<= 1) {
        int t = (tid >= off) ? sd[tid - off] : 0;
        __syncthreads();
        sd[tid] += t;
        __syncthreads();
    }
    if (tid < nb) bsum[tid] = sd[tid] - v;   // exclusive
}

__global__ void rowptr_kernel(const int* __restrict__ deg, const int* __restrict__ bofs,
                              int n, int* __restrict__ rowptr, int* __restrict__ cursor) {
    __shared__ int sd[256];
    int tid = threadIdx.x;
    int i = blockIdx.x * 256 + tid;
    int v = (i < n) ? deg[i] : 0;
    sd[tid] = v;
    __syncthreads();
    for (int off = 1; off < 256; off <<= 1) {
        int t = (tid >= off) ? sd[tid - off] : 0;
        __syncthreads();
        sd[tid] += t;
        __syncthreads();
    }
    int excl = bofs[blockIdx.x] + sd[tid] - v;
    if (i < n) { rowptr[i] = excl; cursor[i] = excl; }
    if (i == n - 1) rowptr[n] = excl + v;
}

__global__ void scatter_kernel(const int* __restrict__ ei, int E, int Et,
                               int* __restrict__ cursor, int* __restrict__ srcs) {
    int e = blockIdx.x * blockDim.x + threadIdx.x;
    if (e >= Et) return;
    int src, dst;
    if (e < E) { src = ei[e]; dst = ei[E + e]; }
    else       { src = dst = e - E; }
    int pos = atomicAdd(&cursor[dst], 1);
    srcs[pos] = src;
}

// ====== fused per-dst gather: scores + online softmax + aggregate =============
// one wave per dst node; lanes hold VPL features each; head = contiguous LPH lanes
template <int H, int C, int VPL>
__global__ __launch_bounds__(256) void gat_gather_kernel(
        const float* __restrict__ xl, const float* __restrict__ xr,
        const float* __restrict__ att,
        const int* __restrict__ rowptr, const int* __restrict__ srcs,
        float* __restrict__ out, int n) {
    int wid = (blockIdx.x * 256 + threadIdx.x) >> 6;
    int lane = threadIdx.x & 63;
    if (wid >= n) return;
    constexpr int HC = H * C;
    constexpr int LPH = C / VPL;   // lanes per head group (16 or 64)
    int base = lane * VPL;

    float xrv[VPL], av[VPL];
#pragma unroll
    for (int v = 0; v < VPL; v++) {
        xrv[v] = xr[(size_t)wid * HC + base + v];
        av[v] = att[base + v];
    }
    float m = -3.0e38f, denom = 0.0f;
    float acc[VPL];
#pragma unroll
    for (int v = 0; v < VPL; v++) acc[v] = 0.0f;

    int beg = rowptr[wid], end = rowptr[wid + 1];
    for (int chunk = beg; chunk < end; chunk += 64) {
        int cn = min(64, end - chunk);
        int my_src = (chunk + lane < end) ? srcs[chunk + lane] : 0;
        for (int j = 0; j < cn; j++) {
            int src = __shfl(my_src, j, 64);
            float xlv[VPL];
            if (VPL == 2) {
                float2 t = *(const float2*)&xl[(size_t)src * HC + base];
                xlv[0] = t.x; xlv[1] = t.y;
            } else {
                xlv[0] = xl[(size_t)src * HC + base];
            }
            float s = 0.0f;
#pragma unroll
            for (int v = 0; v < VPL; v++) {
                float u = xlv[v] + xrv[v];
                u = (u >= 0.0f) ? u : SLOPE * u;
                s += u * av[v];
            }
#pragma unroll
            for (int off = 1; off < LPH; off <<= 1) s += __shfl_xor(s, off, 64);
            float mn = fmaxf(m, s);
            float scale = __expf(m - mn);
            float p = __expf(s - mn);
            denom = denom * scale + p;
#pragma unroll
            for (int v = 0; v < VPL; v++) acc[v] = acc[v] * scale + p * xlv[v];
            m = mn;
        }
    }
    float inv = 1.0f / denom;
    if (VPL == 2) {
        float2 o = make_float2(acc[0] * inv, acc[1] * inv);
        *(float2*)&out[(size_t)wid * HC + base] = o;
    } else {
        out[(size_t)wid * HC + base] = acc[0] * inv;
    }
}

// ---------------- fused classifier: relu(v@W1+b1)@W2+b2 ----------------------
__global__ __launch_bounds__(256) void classifier_kernel(
        const float* __restrict__ out2, const float* __restrict__ bias2,
        const float* __restrict__ W1, const float* __restrict__ b1,
        const float* __restrict__ W2, const float* __restrict__ b2,
        float* __restrict__ y, int n) {
    __shared__ float sW1[64 * 32];
    __shared__ float sW2[32 * 64];
    __shared__ float sb1[32], sb2[64], sbias2[64];
    int t = threadIdx.x;
    for (int i = t; i < 2048; i += 256) { sW1[i] = W1[i]; sW2[i] = W2[i]; }
    if (t < 32) sb1[t] = b1[t];
    if (t < 64) { sb2[t] = b2[t]; sbias2[t] = bias2[t]; }
    __syncthreads();
    int node = blockIdx.x * blockDim.x + t;
    if (node >= n) return;
    float v[64];
    const float4* src4 = (const float4*)&out2[(size_t)node * 64];
#pragma unroll
    for (int i = 0; i < 16; i++) {
        float4 f = src4[i];
        v[4 * i + 0] = f.x + sbias2[4 * i + 0];
        v[4 * i + 1] = f.y + sbias2[4 * i + 1];
        v[4 * i + 2] = f.z + sbias2[4 * i + 2];
        v[4 * i + 3] = f.w + sbias2[4 * i + 3];
    }
    float hid[32];
#pragma unroll
    for (int j = 0; j < 32; j++) {
        float s = sb1[j];
#pragma unroll
        for (int i = 0; i < 64; i++) s += v[i] * sW1[i * 32 + j];
        hid[j] = fmaxf(s, 0.0f);
    }
    float4* y4 = (float4*)&y[(size_t)node * 64];
#pragma unroll
    for (int o4 = 0; o4 < 16; o4++) {
        float4 o;
#pragma unroll
        for (int j = 0; j < 4; j++) {
            int o_ = o4 * 4 + j;
            float s = sb2[o_];
#pragma unroll
            for (int k = 0; k < 32; k++) s += hid[k] * sW2[k * 64 + o_];
            (&o.x)[j] = s;
        }
        y4[o4] = o;
    }
}

// =============================================================================
extern "C" void kernel_launch(void* const* d_in, const int* in_sizes, int n_in,
                              void* d_out, int out_size, void* d_ws, size_t ws_size,
                              hipStream_t stream) {
    const float* x        = (const float*)d_in[0];
    const int*   ei       = (const int*)d_in[1];
    const float* bn_in_g  = (const float*)d_in[2];
    const float* bn_in_b  = (const float*)d_in[3];
    const float* c0_Wl    = (const float*)d_in[4];
    const float* c0_bl    = (const float*)d_in[5];
    const float* c0_Wr    = (const float*)d_in[6];
    const float* c0_br    = (const float*)d_in[7];
    const float* c0_att   = (const float*)d_in[8];
    const float* c0_bias  = (const float*)d_in[9];
    const float* bn0_g    = (const float*)d_in[10];
    const float* bn0_b    = (const float*)d_in[11];
    const float* c1_Wl    = (const float*)d_in[12];
    const float* c1_bl    = (const float*)d_in[13];
    const float* c1_Wr    = (const float*)d_in[14];
    const float* c1_br    = (const float*)d_in[15];
    const float* c1_att   = (const float*)d_in[16];
    const float* c1_bias  = (const float*)d_in[17];
    const float* bn1_g    = (const float*)d_in[18];
    const float* bn1_b    = (const float*)d_in[19];
    const float* c2_Wl    = (const float*)d_in[20];
    const float* c2_bl    = (const float*)d_in[21];
    const float* c2_Wr    = (const float*)d_in[22];
    const float* c2_br    = (const float*)d_in[23];
    const float* c2_att   = (const float*)d_in[24];
    const float* c2_bias  = (const float*)d_in[25];
    const float* cls_w1   = (const float*)d_in[26];
    const float* cls_b1   = (const float*)d_in[27];
    const float* cls_w2   = (const float*)d_in[28];
    const float* cls_b2   = (const float*)d_in[29];

    const int N = in_sizes[0] / 128;
    const int E = in_sizes[1] / 2;
    const int Et = E + N;

    float* ws = (float*)d_ws;
    size_t off = 0;
    auto alloc = [&](size_t nf) { float* p = ws + off; off += nf; return p; };
    float* hA     = alloc((size_t)N * 128);
    float* xlb    = alloc((size_t)N * 128);
    float* xrb    = alloc((size_t)N * 128);
    float* outb   = alloc((size_t)N * 128);
    float* stats  = alloc(256);
    int* deg      = (int*)alloc(N);
    int* rowptr   = (int*)alloc(N + 1);
    int* cursor   = (int*)alloc(N);
    int* srcs     = (int*)alloc(Et);
    int* bsum     = (int*)alloc(256);

    const int et_blocks = (Et + 255) / 256;
    const int elem128   = (N * 32 + 255) / 256;
    const int nb        = (N + 255) / 256;            // scan blocks (<=256 required)
    const int gw128     = (N + 3) / 4;                // gather: 1 wave/node, 4 waves/block
    dim3 gemm_grid_128(2, (N + 63) / 64);
    dim3 gemm_grid_64(1, (N + 63) / 64);

    // ---- CSR build (once; graph shared by all layers) ----
    hipMemsetAsync(deg, 0, (size_t)N * sizeof(int), stream);
    degree_kernel<<<et_blocks, 256, 0, stream>>>(ei, E, Et, deg);
    blocksum_kernel<<<nb, 256, 0, stream>>>(deg, N, bsum);
    scanb_kernel<<<1, 256, 0, stream>>>(bsum, nb);
    rowptr_kernel<<<nb, 256, 0, stream>>>(deg, bsum, N, rowptr, cursor);
    scatter_kernel<<<et_blocks, 256, 0, stream>>>(ei, E, Et, cursor, srcs);

    // ---- input BN ----
    hipMemsetAsync(stats, 0, 256 * sizeof(float), stream);
    col_stats_kernel<<<512, 128, 0, stream>>>(const_cast<float*>(x), nullptr, stats, N, 128);
    bn_apply_kernel<<<elem128, 256, 0, stream>>>((const float4*)x, stats, bn_in_g, bn_in_b,
                                                 (float4*)hA, N, 128);

    float* h = hA;

    // ================= layer 0 =================
    gemm_bias_kernel<<<gemm_grid_128, 256, 0, stream>>>(h, c0_Wl, c0_bl, xlb, N, 128);
    gemm_bias_kernel<<<gemm_grid_128, 256, 0, stream>>>(h, c0_Wr, c0_br, xrb, N, 128);
    gat_gather_kernel<4, 32, 2><<<gw128, 256, 0, stream>>>(xlb, xrb, c0_att, rowptr, srcs, outb, N);
    hipMemsetAsync(stats, 0, 256 * sizeof(float), stream);
    col_stats_kernel<<<512, 128, 0, stream>>>(outb, c0_bias, stats, N, 128);
    bn_elu_res_kernel<<<elem128, 256, 0, stream>>>((const float4*)outb, stats, bn0_g, bn0_b,
                                                   (const float4*)h, (float4*)xrb, N, 128);
    h = xrb;  // hA now free

    // ================= layer 1 =================
    gemm_bias_kernel<<<gemm_grid_128, 256, 0, stream>>>(h, c1_Wl, c1_bl, xlb, N, 128);
    gemm_bias_kernel<<<gemm_grid_128, 256, 0, stream>>>(h, c1_Wr, c1_br, hA, N, 128);
    gat_gather_kernel<4, 32, 2><<<gw128, 256, 0, stream>>>(xlb, hA, c1_att, rowptr, srcs, outb, N);
    hipMemsetAsync(stats, 0, 256 * sizeof(float), stream);
    col_stats_kernel<<<512, 128, 0, stream>>>(outb, c1_bias, stats, N, 128);
    bn_elu_res_kernel<<<elem128, 256, 0, stream>>>((const float4*)outb, stats, bn1_g, bn1_b,
                                                   (const float4*)h, (float4*)hA, N, 128);
    h = hA;

    // ================= layer 2 (H=1, C=64) =================
    gemm_bias_kernel<<<gemm_grid_64, 256, 0, stream>>>(h, c2_Wl, c2_bl, xlb, N, 64);
    gemm_bias_kernel<<<gemm_grid_64, 256, 0, stream>>>(h, c2_Wr, c2_br, xrb, N, 64);
    gat_gather_kernel<1, 64, 1><<<gw128, 256, 0, stream>>>(xlb, xrb, c2_att, rowptr, srcs, outb, N);

    // ---- classifier (fuses conv2 bias) ----
    classifier_kernel<<<(N + 255) / 256, 256, 0, stream>>>(outb, c2_bias, cls_w1, cls_b1,
                                                           cls_w2, cls_b2, (float*)d_out, N);
}

// Round 7
// 733.474 us; speedup vs baseline: 4.2550x; 1.3781x over previous
//
#include <hip/hip_runtime.h>
#include <math.h>

typedef __attribute__((ext_vector_type(8))) short short8;
typedef __attribute__((ext_vector_type(4))) float f32x4;

constexpr float EPS_BN = 1e-5f;
constexpr float SLOPE = 0.2f;

__device__ __forceinline__ unsigned short f2bf_rne(float f) {
    unsigned u = __float_as_uint(f);
    unsigned r = ((u >> 16) & 1u) + 0x7fffu;
    return (unsigned short)((u + r) >> 16);
}
__device__ __forceinline__ float bf2f(unsigned short h) {
    return __uint_as_float(((unsigned)h) << 16);
}

// ---------------- column stats (read-only) ------------------------------------
__global__ void col_stats_kernel(const float* __restrict__ data,
                                 float* __restrict__ stats, int n, int c) {
    int f = threadIdx.x;
    float s = 0.0f, q = 0.0f;
    for (int r = blockIdx.x; r < n; r += gridDim.x) {
        float v = data[(size_t)r * c + f];
        s += v;
        q += v * v;
    }
    atomicAdd(&stats[f], s);
    atomicAdd(&stats[c + f], q);
}

// ---------------- BN apply (input) -------------------------------------------
__global__ void bn_apply_kernel(const float4* __restrict__ x, const float* __restrict__ stats,
                                const float* __restrict__ g, const float* __restrict__ b,
                                float4* __restrict__ h, int n, int c) {
    int c4 = c / 4;
    int i = blockIdx.x * blockDim.x + threadIdx.x;
    if (i >= n * c4) return;
    int f = (i % c4) * 4;
    float4 v = x[i];
    float4 o;
    float invn = 1.0f / (float)n;
#pragma unroll
    for (int j = 0; j < 4; j++) {
        float mean = stats[f + j] * invn;
        float var = stats[c + f + j] * invn - mean * mean;
        float rs = rsqrtf(var + EPS_BN);
        float xv = (&v.x)[j];
        (&o.x)[j] = g[f + j] * (xv - mean) * rs + b[f + j];
    }
    h[i] = o;
}

// ---------------- BN + ELU + residual ----------------------------------------
__global__ void bn_elu_res_kernel(const float4* __restrict__ out, const float* __restrict__ stats,
                                  const float* __restrict__ g, const float* __restrict__ b,
                                  const float4* __restrict__ res, float4* __restrict__ dst,
                                  int n, int c) {
    int c4 = c / 4;
    int i = blockIdx.x * blockDim.x + threadIdx.x;
    if (i >= n * c4) return;
    int f = (i % c4) * 4;
    float4 v = out[i];
    float4 r = res[i];
    float4 o;
    float invn = 1.0f / (float)n;
#pragma unroll
    for (int j = 0; j < 4; j++) {
        float mean = stats[f + j] * invn;
        float var = stats[c + f + j] * invn - mean * mean;
        float rs = rsqrtf(var + EPS_BN);
        float y = g[f + j] * ((&v.x)[j] - mean) * rs + b[f + j];
        float e = (y > 0.0f) ? y : expm1f(y);
        (&o.x)[j] = e + (&r.x)[j];
    }
    dst[i] = o;
}

// ---------------- MFMA GEMM: Y[n x m] = X[n x 128] @ W[128 x m] + bias --------
// bf16 split: X ~= Xh+Xl, W ~= Wh+Wl; Y = Xh*Wh + Xh*Wl + Xl*Wh (~fp32 accurate).
// Block tile 64x64, 4 waves (2x2 of 32x32). A/B staged in FRAGMENT ORDER so every
// LDS access is a conflict-free per-lane-contiguous b128. K=128 in 2 halves.
// Fragment layouts (mfma_f32_16x16x32_bf16):
//   A: row = lane&15, k = (lane>>4)*8 + j      B: col = lane&15, same k
//   D: col = lane&15, row = (lane>>4)*4 + reg  (HW-verified, m89)
__global__ __launch_bounds__(256) void gemm_mfma_kernel(
        const float* __restrict__ X, const float* __restrict__ W,
        const float* __restrict__ bias, float* __restrict__ Y, int n, int m) {
    __shared__ short sA[2][2][4][64][8];   // [hi/lo][ks2][rowblk][lane][j]
    __shared__ short sB[2][2][4][64][8];   // [hi/lo][ks2][colblk][lane][j]
    int t = threadIdx.x;
    int col0 = blockIdx.x * 64;
    int row0 = blockIdx.y * 64;
    int wid = t >> 6, lane = t & 63;
    int wr = wid >> 1, wc = wid & 1;

    f32x4 acc[2][2];
#pragma unroll
    for (int i = 0; i < 2; i++)
#pragma unroll
        for (int j = 0; j < 2; j++) acc[i][j] = (f32x4){0.f, 0.f, 0.f, 0.f};

    for (int half = 0; half < 2; half++) {
        // ---- stage A (X tile rows row0..row0+63, k half) ----
#pragma unroll
        for (int s0 = 0; s0 < 2; s0++) {
            int s = t + s0 * 256;                 // 512 slots
            int l = s & 63, rb = (s >> 6) & 3, ks2 = s >> 8;
            int row = row0 + rb * 16 + (l & 15);
            int kb = (half * 2 + ks2) * 32 + (l >> 4) * 8;
            short8 hv = {}; short8 lv = {};
            if (row < n) {
                const float4* p = (const float4*)&X[(size_t)row * 128 + kb];
                float4 v0 = p[0], v1 = p[1];
#pragma unroll
                for (int j = 0; j < 4; j++) {
                    float f0 = (&v0.x)[j];
                    unsigned short h0 = f2bf_rne(f0);
                    hv[j] = (short)h0;
                    lv[j] = (short)f2bf_rne(f0 - bf2f(h0));
                    float f1 = (&v1.x)[j];
                    unsigned short h1 = f2bf_rne(f1);
                    hv[4 + j] = (short)h1;
                    lv[4 + j] = (short)f2bf_rne(f1 - bf2f(h1));
                }
            }
            *(short8*)&sA[0][ks2][rb][l][0] = hv;
            *(short8*)&sA[1][ks2][rb][l][0] = lv;
        }
        // ---- stage B (W k-half, cols col0..col0+63) ----
#pragma unroll
        for (int s0 = 0; s0 < 2; s0++) {
            int s = t + s0 * 256;
            int l = s & 63, nb = (s >> 6) & 3, ks2 = s >> 8;
            int col = col0 + nb * 16 + (l & 15);
            int kb = (half * 2 + ks2) * 32 + (l >> 4) * 8;
            short8 hv, lv;
#pragma unroll
            for (int j = 0; j < 8; j++) {
                float f = W[(size_t)(kb + j) * m + col];
                unsigned short h = f2bf_rne(f);
                hv[j] = (short)h;
                lv[j] = (short)f2bf_rne(f - bf2f(h));
            }
            *(short8*)&sB[0][ks2][nb][l][0] = hv;
            *(short8*)&sB[1][ks2][nb][l][0] = lv;
        }
        __syncthreads();
#pragma unroll
        for (int ks2 = 0; ks2 < 2; ks2++) {
            short8 Ah[2], Al[2], Bh[2], Bl[2];
#pragma unroll
            for (int mr = 0; mr < 2; mr++) {
                Ah[mr] = *(const short8*)&sA[0][ks2][wr * 2 + mr][lane][0];
                Al[mr] = *(const short8*)&sA[1][ks2][wr * 2 + mr][lane][0];
            }
#pragma unroll
            for (int nr = 0; nr < 2; nr++) {
                Bh[nr] = *(const short8*)&sB[0][ks2][wc * 2 + nr][lane][0];
                Bl[nr] = *(const short8*)&sB[1][ks2][wc * 2 + nr][lane][0];
            }
#pragma unroll
            for (int mr = 0; mr < 2; mr++)
#pragma unroll
                for (int nr = 0; nr < 2; nr++) {
                    acc[mr][nr] = __builtin_amdgcn_mfma_f32_16x16x32_bf16(Ah[mr], Bh[nr], acc[mr][nr], 0, 0, 0);
                    acc[mr][nr] = __builtin_amdgcn_mfma_f32_16x16x32_bf16(Ah[mr], Bl[nr], acc[mr][nr], 0, 0, 0);
                    acc[mr][nr] = __builtin_amdgcn_mfma_f32_16x16x32_bf16(Al[mr], Bh[nr], acc[mr][nr], 0, 0, 0);
                }
        }
        __syncthreads();
    }
    // ---- epilogue ----
    int cbase = col0 + wc * 32 + (lane & 15);
#pragma unroll
    for (int mr = 0; mr < 2; mr++)
#pragma unroll
        for (int nr = 0; nr < 2; nr++) {
            int col = cbase + nr * 16;
            float bv = bias[col];
#pragma unroll
            for (int r = 0; r < 4; r++) {
                int row = row0 + wr * 32 + mr * 16 + (lane >> 4) * 4 + r;
                if (row < n) Y[(size_t)row * m + col] = acc[mr][nr][r] + bv;
            }
        }
}

// ================= CSR build (graph identical for all 3 layers) ===============
__global__ void degree_kernel(const int* __restrict__ ei, int E, int Et, int* __restrict__ deg) {
    int e = blockIdx.x * blockDim.x + threadIdx.x;
    if (e >= Et) return;
    int dst = (e < E) ? ei[E + e] : e - E;
    atomicAdd(&deg[dst], 1);
}

__global__ void blocksum_kernel(const int* __restrict__ deg, int n, int* __restrict__ bsum) {
    __shared__ int sd[256];
    int i = blockIdx.x * 256 + threadIdx.x;
    sd[threadIdx.x] = (i < n) ? deg[i] : 0;
    __syncthreads();
    for (int s = 128; s > 0; s >>= 1) {
        if (threadIdx.x < s) sd[threadIdx.x] += sd[threadIdx.x + s];
        __syncthreads();
    }
    if (threadIdx.x == 0) bsum[blockIdx.x] = sd[0];
}

__global__ void scanb_kernel(int* __restrict__ bsum, int nb) {
    __shared__ int sd[256];
    int tid = threadIdx.x;
    int v = (tid < nb) ? bsum[tid] : 0;
    sd[tid] = v;
    __syncthreads();
    for (int off = 1; off < 256; off <<= 1) {
        int t = (tid >= off) ? sd[tid - off] : 0;
        __syncthreads();
        sd[tid] += t;
        __syncthreads();
    }
    if (tid < nb) bsum[tid] = sd[tid] - v;   // exclusive
}

__global__ void rowptr_kernel(const int* __restrict__ deg, const int* __restrict__ bofs,
                              int n, int* __restrict__ rowptr, int* __restrict__ cursor) {
    __shared__ int sd[256];
    int tid = threadIdx.x;
    int i = blockIdx.x * 256 + tid;
    int v = (i < n) ? deg[i] : 0;
    sd[tid] = v;
    __syncthreads();
    for (int off = 1; off < 256; off <<= 1) {
        int t = (tid >= off) ? sd[tid - off] : 0;
        __syncthreads();
        sd[tid] += t;
        __syncthreads();
    }
    int excl = bofs[blockIdx.x] + sd[tid] - v;
    if (i < n) { rowptr[i] = excl; cursor[i] = excl; }
    if (i == n - 1) rowptr[n] = excl + v;
}

__global__ void scatter_kernel(const int* __restrict__ ei, int E, int Et,
                               int* __restrict__ cursor, int* __restrict__ srcs) {
    int e = blockIdx.x * blockDim.x + threadIdx.x;
    if (e >= Et) return;
    int src, dst;
    if (e < E) { src = ei[e]; dst = ei[E + e]; }
    else       { src = dst = e - E; }
    int pos = atomicAdd(&cursor[dst], 1);
    srcs[pos] = src;
}

// ====== fused per-dst gather: scores + deferred-max softmax + aggregate =======
// one wave per dst node; defer-max (m0=0, THR=8): rescale almost never fires.
template <int H, int C, int VPL>
__global__ __launch_bounds__(256) void gat_gather_kernel(
        const float* __restrict__ xl, const float* __restrict__ xr,
        const float* __restrict__ att, const float* __restrict__ bias,
        const int* __restrict__ rowptr, const int* __restrict__ srcs,
        float* __restrict__ out, int n) {
    int wid = (blockIdx.x * 256 + threadIdx.x) >> 6;
    int lane = threadIdx.x & 63;
    if (wid >= n) return;
    constexpr int HC = H * C;
    constexpr int LPH = C / VPL;   // lanes per head group
    int base = lane * VPL;

    float xrv[VPL], av[VPL];
#pragma unroll
    for (int v = 0; v < VPL; v++) {
        xrv[v] = xr[(size_t)wid * HC + base + v];
        av[v] = att[base + v];
    }
    float m = 0.0f, denom = 0.0f;
    float acc[VPL];
#pragma unroll
    for (int v = 0; v < VPL; v++) acc[v] = 0.0f;

    int beg = rowptr[wid], end = rowptr[wid + 1];
    for (int chunk = beg; chunk < end; chunk += 64) {
        int cn = min(64, end - chunk);
        int my_src = (chunk + lane < end) ? srcs[chunk + lane] : 0;
        // 1-deep software pipeline on the xl row load
        int src = __shfl(my_src, 0, 64);
        float xlv[VPL];
        if (VPL == 2) {
            float2 tv = *(const float2*)&xl[(size_t)src * HC + base];
            xlv[0] = tv.x; xlv[1] = tv.y;
        } else {
            xlv[0] = xl[(size_t)src * HC + base];
        }
        for (int j = 0; j < cn; j++) {
            float nxt[VPL];
            int nj = (j + 1 < cn) ? j + 1 : j;
            int nsrc = __shfl(my_src, nj, 64);
            if (VPL == 2) {
                float2 tv = *(const float2*)&xl[(size_t)nsrc * HC + base];
                nxt[0] = tv.x; nxt[1] = tv.y;
            } else {
                nxt[0] = xl[(size_t)nsrc * HC + base];
            }
            float s = 0.0f;
#pragma unroll
            for (int v = 0; v < VPL; v++) {
                float u = xlv[v] + xrv[v];
                u = (u >= 0.0f) ? u : SLOPE * u;
                s += u * av[v];
            }
#pragma unroll
            for (int off = 1; off < LPH; off <<= 1) s += __shfl_xor(s, off, 64);
            if (s > m + 8.0f) {           // defer-max rescue (rarely taken)
                float sc = __expf(m - s);
                denom *= sc;
#pragma unroll
                for (int v = 0; v < VPL; v++) acc[v] *= sc;
                m = s;
            }
            float p = __expf(s - m);
            denom += p;
#pragma unroll
            for (int v = 0; v < VPL; v++) acc[v] = fmaf(p, xlv[v], acc[v]);
#pragma unroll
            for (int v = 0; v < VPL; v++) xlv[v] = nxt[v];
        }
    }
    float inv = 1.0f / denom;
    if (VPL == 2) {
        float2 o = make_float2(acc[0] * inv + bias[base], acc[1] * inv + bias[base + 1]);
        *(float2*)&out[(size_t)wid * HC + base] = o;
    } else {
        out[(size_t)wid * HC + base] = acc[0] * inv + bias[base];
    }
}

// ---------------- fused classifier: relu(v@W1+b1)@W2+b2 ----------------------
__global__ __launch_bounds__(256) void classifier_kernel(
        const float* __restrict__ out2,
        const float* __restrict__ W1, const float* __restrict__ b1,
        const float* __restrict__ W2, const float* __restrict__ b2,
        float* __restrict__ y, int n) {
    __shared__ float sW1[64 * 32];
    __shared__ float sW2[32 * 64];
    __shared__ float sb1[32], sb2[64];
    int t = threadIdx.x;
    for (int i = t; i < 2048; i += 256) { sW1[i] = W1[i]; sW2[i] = W2[i]; }
    if (t < 32) sb1[t] = b1[t];
    if (t < 64) sb2[t] = b2[t];
    __syncthreads();
    int node = blockIdx.x * blockDim.x + t;
    if (node >= n) return;
    float v[64];
    const float4* src4 = (const float4*)&out2[(size_t)node * 64];
#pragma unroll
    for (int i = 0; i < 16; i++) {
        float4 f = src4[i];
        v[4 * i + 0] = f.x; v[4 * i + 1] = f.y; v[4 * i + 2] = f.z; v[4 * i + 3] = f.w;
    }
    float hid[32];
#pragma unroll
    for (int j = 0; j < 32; j++) {
        float s = sb1[j];
#pragma unroll
        for (int i = 0; i < 64; i++) s += v[i] * sW1[i * 32 + j];
        hid[j] = fmaxf(s, 0.0f);
    }
    float4* y4 = (float4*)&y[(size_t)node * 64];
#pragma unroll
    for (int o4 = 0; o4 < 16; o4++) {
        float4 o;
#pragma unroll
        for (int j = 0; j < 4; j++) {
            int o_ = o4 * 4 + j;
            float s = sb2[o_];
#pragma unroll
            for (int k = 0; k < 32; k++) s += hid[k] * sW2[k * 64 + o_];
            (&o.x)[j] = s;
        }
        y4[o4] = o;
    }
}

// =============================================================================
extern "C" void kernel_launch(void* const* d_in, const int* in_sizes, int n_in,
                              void* d_out, int out_size, void* d_ws, size_t ws_size,
                              hipStream_t stream) {
    const float* x        = (const float*)d_in[0];
    const int*   ei       = (const int*)d_in[1];
    const float* bn_in_g  = (const float*)d_in[2];
    const float* bn_in_b  = (const float*)d_in[3];
    const float* c0_Wl    = (const float*)d_in[4];
    const float* c0_bl    = (const float*)d_in[5];
    const float* c0_Wr    = (const float*)d_in[6];
    const float* c0_br    = (const float*)d_in[7];
    const float* c0_att   = (const float*)d_in[8];
    const float* c0_bias  = (const float*)d_in[9];
    const float* bn0_g    = (const float*)d_in[10];
    const float* bn0_b    = (const float*)d_in[11];
    const float* c1_Wl    = (const float*)d_in[12];
    const float* c1_bl    = (const float*)d_in[13];
    const float* c1_Wr    = (const float*)d_in[14];
    const float* c1_br    = (const float*)d_in[15];
    const float* c1_att   = (const float*)d_in[16];
    const float* c1_bias  = (const float*)d_in[17];
    const float* bn1_g    = (const float*)d_in[18];
    const float* bn1_b    = (const float*)d_in[19];
    const float* c2_Wl    = (const float*)d_in[20];
    const float* c2_bl    = (const float*)d_in[21];
    const float* c2_Wr    = (const float*)d_in[22];
    const float* c2_br    = (const float*)d_in[23];
    const float* c2_att   = (const float*)d_in[24];
    const float* c2_bias  = (const float*)d_in[25];
    const float* cls_w1   = (const float*)d_in[26];
    const float* cls_b1   = (const float*)d_in[27];
    const float* cls_w2   = (const float*)d_in[28];
    const float* cls_b2   = (const float*)d_in[29];

    const int N = in_sizes[0] / 128;
    const int E = in_sizes[1] / 2;
    const int Et = E + N;

    float* ws = (float*)d_ws;
    size_t off = 0;
    auto alloc = [&](size_t nf) { float* p = ws + off; off += nf; return p; };
    float* hA     = alloc((size_t)N * 128);
    float* xlb    = alloc((size_t)N * 128);
    float* xrb    = alloc((size_t)N * 128);
    float* outb   = alloc((size_t)N * 128);
    float* stats  = alloc(256);
    int* deg      = (int*)alloc(N);
    int* rowptr   = (int*)alloc(N + 1);
    int* cursor   = (int*)alloc(N);
    int* srcs     = (int*)alloc(Et);
    int* bsum     = (int*)alloc(256);

    const int et_blocks = (Et + 255) / 256;
    const int elem128   = (N * 32 + 255) / 256;
    const int nb        = (N + 255) / 256;
    const int gw        = (N + 3) / 4;                // gather: 1 wave/node
    dim3 gemm_grid_128(2, (N + 63) / 64);
    dim3 gemm_grid_64(1, (N + 63) / 64);

    // ---- CSR build (once; graph shared by all layers) ----
    hipMemsetAsync(deg, 0, (size_t)N * sizeof(int), stream);
    degree_kernel<<<et_blocks, 256, 0, stream>>>(ei, E, Et, deg);
    blocksum_kernel<<<nb, 256, 0, stream>>>(deg, N, bsum);
    scanb_kernel<<<1, 256, 0, stream>>>(bsum, nb);
    rowptr_kernel<<<nb, 256, 0, stream>>>(deg, bsum, N, rowptr, cursor);
    scatter_kernel<<<et_blocks, 256, 0, stream>>>(ei, E, Et, cursor, srcs);

    // ---- input BN ----
    hipMemsetAsync(stats, 0, 256 * sizeof(float), stream);
    col_stats_kernel<<<512, 128, 0, stream>>>(x, stats, N, 128);
    bn_apply_kernel<<<elem128, 256, 0, stream>>>((const float4*)x, stats, bn_in_g, bn_in_b,
                                                 (float4*)hA, N, 128);

    float* h = hA;

    // ================= layer 0 =================
    gemm_mfma_kernel<<<gemm_grid_128, 256, 0, stream>>>(h, c0_Wl, c0_bl, xlb, N, 128);
    gemm_mfma_kernel<<<gemm_grid_128, 256, 0, stream>>>(h, c0_Wr, c0_br, xrb, N, 128);
    gat_gather_kernel<4, 32, 2><<<gw, 256, 0, stream>>>(xlb, xrb, c0_att, c0_bias, rowptr, srcs, outb, N);
    hipMemsetAsync(stats, 0, 256 * sizeof(float), stream);
    col_stats_kernel<<<512, 128, 0, stream>>>(outb, stats, N, 128);
    bn_elu_res_kernel<<<elem128, 256, 0, stream>>>((const float4*)outb, stats, bn0_g, bn0_b,
                                                   (const float4*)h, (float4*)xrb, N, 128);
    h = xrb;  // hA now free

    // ================= layer 1 =================
    gemm_mfma_kernel<<<gemm_grid_128, 256, 0, stream>>>(h, c1_Wl, c1_bl, xlb, N, 128);
    gemm_mfma_kernel<<<gemm_grid_128, 256, 0, stream>>>(h, c1_Wr, c1_br, hA, N, 128);
    gat_gather_kernel<4, 32, 2><<<gw, 256, 0, stream>>>(xlb, hA, c1_att, c1_bias, rowptr, srcs, outb, N);
    hipMemsetAsync(stats, 0, 256 * sizeof(float), stream);
    col_stats_kernel<<<512, 128, 0, stream>>>(outb, stats, N, 128);
    bn_elu_res_kernel<<<elem128, 256, 0, stream>>>((const float4*)outb, stats, bn1_g, bn1_b,
                                                   (const float4*)h, (float4*)hA, N, 128);
    h = hA;

    // ================= layer 2 (H=1, C=64) =================
    gemm_mfma_kernel<<<gemm_grid_64, 256, 0, stream>>>(h, c2_Wl, c2_bl, xlb, N, 64);
    gemm_mfma_kernel<<<gemm_grid_64, 256, 0, stream>>>(h, c2_Wr, c2_br, xrb, N, 64);
    gat_gather_kernel<1, 64, 1><<<gw, 256, 0, stream>>>(xlb, xrb, c2_att, c2_bias, rowptr, srcs, outb, N);

    // ---- classifier (conv2 bias already fused into gather) ----
    classifier_kernel<<<(N + 255) / 256, 256, 0, stream>>>(outb, cls_w1, cls_b1,
                                                           cls_w2, cls_b2, (float*)d_out, N);
}

// Round 11
// 677.388 us; speedup vs baseline: 4.6073x; 1.0828x over previous
//
#include <hip/hip_runtime.h>
#include <math.h>

typedef __attribute__((ext_vector_type(8))) short short8;
typedef __attribute__((ext_vector_type(4))) float f32x4;

constexpr float EPS_BN = 1e-5f;
constexpr float SLOPE = 0.2f;

__device__ __forceinline__ unsigned short f2bf_rne(float f) {
    unsigned u = __float_as_uint(f);
    unsigned r = ((u >> 16) & 1u) + 0x7fffu;
    return (unsigned short)((u + r) >> 16);
}
__device__ __forceinline__ float bf2f(unsigned short h) {
    return __uint_as_float(((unsigned)h) << 16);
}

// ---------------- column stats (read-only) ------------------------------------
__global__ void col_stats_kernel(const float* __restrict__ data,
                                 float* __restrict__ stats, int n, int c) {
    int f = threadIdx.x;
    float s = 0.0f, q = 0.0f;
    for (int r = blockIdx.x; r < n; r += gridDim.x) {
        float v = data[(size_t)r * c + f];
        s += v;
        q += v * v;
    }
    atomicAdd(&stats[f], s);
    atomicAdd(&stats[c + f], q);
}

// ---------------- BN apply (input) -------------------------------------------
__global__ void bn_apply_kernel(const float4* __restrict__ x, const float* __restrict__ stats,
                                const float* __restrict__ g, const float* __restrict__ b,
                                float4* __restrict__ h, int n, int c) {
    int c4 = c / 4;
    int i = blockIdx.x * blockDim.x + threadIdx.x;
    if (i >= n * c4) return;
    int f = (i % c4) * 4;
    float4 v = x[i];
    float4 o;
    float invn = 1.0f / (float)n;
#pragma unroll
    for (int j = 0; j < 4; j++) {
        float mean = stats[f + j] * invn;
        float var = stats[c + f + j] * invn - mean * mean;
        float rs = rsqrtf(var + EPS_BN);
        float xv = (&v.x)[j];
        (&o.x)[j] = g[f + j] * (xv - mean) * rs + b[f + j];
    }
    h[i] = o;
}

// ---------------- BN + ELU + residual ----------------------------------------
__global__ void bn_elu_res_kernel(const float4* __restrict__ out, const float* __restrict__ stats,
                                  const float* __restrict__ g, const float* __restrict__ b,
                                  const float4* __restrict__ res, float4* __restrict__ dst,
                                  int n, int c) {
    int c4 = c / 4;
    int i = blockIdx.x * blockDim.x + threadIdx.x;
    if (i >= n * c4) return;
    int f = (i % c4) * 4;
    float4 v = out[i];
    float4 r = res[i];
    float4 o;
    float invn = 1.0f / (float)n;
#pragma unroll
    for (int j = 0; j < 4; j++) {
        float mean = stats[f + j] * invn;
        float var = stats[c + f + j] * invn - mean * mean;
        float rs = rsqrtf(var + EPS_BN);
        float y = g[f + j] * ((&v.x)[j] - mean) * rs + b[f + j];
        float e = (y > 0.0f) ? y : expm1f(y);
        (&o.x)[j] = e + (&r.x)[j];
    }
    dst[i] = o;
}

// ---------------- MFMA GEMM: Y[n x m] = X[n x 128] @ W[128 x m] + bias --------
// bf16 split: X ~= Xh+Xl, W ~= Wh+Wl; Y = Xh*Wh + Xh*Wl + Xl*Wh (~fp32 accurate).
__global__ __launch_bounds__(256) void gemm_mfma_kernel(
        const float* __restrict__ X, const float* __restrict__ W,
        const float* __restrict__ bias, float* __restrict__ Y, int n, int m) {
    __shared__ short sA[2][2][4][64][8];   // [hi/lo][ks2][rowblk][lane][j]
    __shared__ short sB[2][2][4][64][8];   // [hi/lo][ks2][colblk][lane][j]
    int t = threadIdx.x;
    int col0 = blockIdx.x * 64;
    int row0 = blockIdx.y * 64;
    int wid = t >> 6, lane = t & 63;
    int wr = wid >> 1, wc = wid & 1;

    f32x4 acc[2][2];
#pragma unroll
    for (int i = 0; i < 2; i++)
#pragma unroll
        for (int j = 0; j < 2; j++) acc[i][j] = (f32x4){0.f, 0.f, 0.f, 0.f};

    for (int half = 0; half < 2; half++) {
#pragma unroll
        for (int s0 = 0; s0 < 2; s0++) {
            int s = t + s0 * 256;
            int l = s & 63, rb = (s >> 6) & 3, ks2 = s >> 8;
            int row = row0 + rb * 16 + (l & 15);
            int kb = (half * 2 + ks2) * 32 + (l >> 4) * 8;
            short8 hv = {}; short8 lv = {};
            if (row < n) {
                const float4* p = (const float4*)&X[(size_t)row * 128 + kb];
                float4 v0 = p[0], v1 = p[1];
#pragma unroll
                for (int j = 0; j < 4; j++) {
                    float f0 = (&v0.x)[j];
                    unsigned short h0 = f2bf_rne(f0);
                    hv[j] = (short)h0;
                    lv[j] = (short)f2bf_rne(f0 - bf2f(h0));
                    float f1 = (&v1.x)[j];
                    unsigned short h1 = f2bf_rne(f1);
                    hv[4 + j] = (short)h1;
                    lv[4 + j] = (short)f2bf_rne(f1 - bf2f(h1));
                }
            }
            *(short8*)&sA[0][ks2][rb][l][0] = hv;
            *(short8*)&sA[1][ks2][rb][l][0] = lv;
        }
#pragma unroll
        for (int s0 = 0; s0 < 2; s0++) {
            int s = t + s0 * 256;
            int l = s & 63, nb = (s >> 6) & 3, ks2 = s >> 8;
            int col = col0 + nb * 16 + (l & 15);
            int kb = (half * 2 + ks2) * 32 + (l >> 4) * 8;
            short8 hv, lv;
#pragma unroll
            for (int j = 0; j < 8; j++) {
                float f = W[(size_t)(kb + j) * m + col];
                unsigned short h = f2bf_rne(f);
                hv[j] = (short)h;
                lv[j] = (short)f2bf_rne(f - bf2f(h));
            }
            *(short8*)&sB[0][ks2][nb][l][0] = hv;
            *(short8*)&sB[1][ks2][nb][l][0] = lv;
        }
        __syncthreads();
#pragma unroll
        for (int ks2 = 0; ks2 < 2; ks2++) {
            short8 Ah[2], Al[2], Bh[2], Bl[2];
#pragma unroll
            for (int mr = 0; mr < 2; mr++) {
                Ah[mr] = *(const short8*)&sA[0][ks2][wr * 2 + mr][lane][0];
                Al[mr] = *(const short8*)&sA[1][ks2][wr * 2 + mr][lane][0];
            }
#pragma unroll
            for (int nr = 0; nr < 2; nr++) {
                Bh[nr] = *(const short8*)&sB[0][ks2][wc * 2 + nr][lane][0];
                Bl[nr] = *(const short8*)&sB[1][ks2][wc * 2 + nr][lane][0];
            }
#pragma unroll
            for (int mr = 0; mr < 2; mr++)
#pragma unroll
                for (int nr = 0; nr < 2; nr++) {
                    acc[mr][nr] = __builtin_amdgcn_mfma_f32_16x16x32_bf16(Ah[mr], Bh[nr], acc[mr][nr], 0, 0, 0);
                    acc[mr][nr] = __builtin_amdgcn_mfma_f32_16x16x32_bf16(Ah[mr], Bl[nr], acc[mr][nr], 0, 0, 0);
                    acc[mr][nr] = __builtin_amdgcn_mfma_f32_16x16x32_bf16(Al[mr], Bh[nr], acc[mr][nr], 0, 0, 0);
                }
        }
        __syncthreads();
    }
    int cbase = col0 + wc * 32 + (lane & 15);
#pragma unroll
    for (int mr = 0; mr < 2; mr++)
#pragma unroll
        for (int nr = 0; nr < 2; nr++) {
            int col = cbase + nr * 16;
            float bv = bias[col];
#pragma unroll
            for (int r = 0; r < 4; r++) {
                int row = row0 + wr * 32 + mr * 16 + (lane >> 4) * 4 + r;
                if (row < n) Y[(size_t)row * m + col] = acc[mr][nr][r] + bv;
            }
        }
}

// ================= CSR build (graph identical for all 3 layers) ===============
__global__ void degree_kernel(const int* __restrict__ ei, int E, int Et, int* __restrict__ deg) {
    int e = blockIdx.x * blockDim.x + threadIdx.x;
    if (e >= Et) return;
    int dst = (e < E) ? ei[E + e] : e - E;
    atomicAdd(&deg[dst], 1);
}

__global__ void blocksum_kernel(const int* __restrict__ deg, int n, int* __restrict__ bsum) {
    __shared__ int sd[256];
    int i = blockIdx.x * 256 + threadIdx.x;
    sd[threadIdx.x] = (i < n) ? deg[i] : 0;
    __syncthreads();
    for (int s = 128; s > 0; s >>= 1) {
        if (threadIdx.x < s) sd[threadIdx.x] += sd[threadIdx.x + s];
        __syncthreads();
    }
    if (threadIdx.x == 0) bsum[blockIdx.x] = sd[0];
}

__global__ void scanb_kernel(int* __restrict__ bsum, int nb) {
    __shared__ int sd[256];
    int tid = threadIdx.x;
    int v = (tid < nb) ? bsum[tid] : 0;
    sd[tid] = v;
    __syncthreads();
    for (int off = 1; off < 256; off <<= 1) {
        int t = (tid >= off) ? sd[tid - off] : 0;
        __syncthreads();
        sd[tid] += t;
        __syncthreads();
    }
    if (tid < nb) bsum[tid] = sd[tid] - v;   // exclusive
}

__global__ void rowptr_kernel(const int* __restrict__ deg, const int* __restrict__ bofs,
                              int n, int* __restrict__ rowptr, int* __restrict__ cursor) {
    __shared__ int sd[256];
    int tid = threadIdx.x;
    int i = blockIdx.x * 256 + tid;
    int v = (i < n) ? deg[i] : 0;
    sd[tid] = v;
    __syncthreads();
    for (int off = 1; off < 256; off <<= 1) {
        int t = (tid >= off) ? sd[tid - off] : 0;
        __syncthreads();
        sd[tid] += t;
        __syncthreads();
    }
    int excl = bofs[blockIdx.x] + sd[tid] - v;
    if (i < n) { rowptr[i] = excl; cursor[i] = excl; }
    if (i == n - 1) rowptr[n] = excl + v;
}

__global__ void scatter_kernel(const int* __restrict__ ei, int E, int Et,
                               int* __restrict__ cursor, int* __restrict__ srcs) {
    int e = blockIdx.x * blockDim.x + threadIdx.x;
    if (e >= Et) return;
    int src, dst;
    if (e < E) { src = ei[e]; dst = ei[E + e]; }
    else       { src = dst = e - E; }
    int pos = atomicAdd(&cursor[dst], 1);
    srcs[pos] = src;
}

// ====== fused per-dst gather: 4 edges/wave, deferred-max online softmax =======
// wave = 4 groups of 16 lanes; group g processes edge slot j*4+g.
// Each lane holds VPL = H*C/16 features. Per-group online-softmax state merged
// at the end via shfl_xor(16/32) online-softmax merge.
template <int H, int C>
__global__ __launch_bounds__(256) void gat_gather_kernel(
        const float* __restrict__ xl, const float* __restrict__ xr,
        const float* __restrict__ att, const float* __restrict__ bias,
        const int* __restrict__ rowptr, const int* __restrict__ srcs,
        float* __restrict__ out, int n) {
    constexpr int HC = H * C;
    constexpr int VPL = HC / 16;     // 8 (HC=128) or 4 (HC=64)
    constexpr int RPH = C / VPL;     // lanes spanning one head: 4 or 16
    int wid = (blockIdx.x * 256 + threadIdx.x) >> 6;
    int lane = threadIdx.x & 63;
    if (wid >= n) return;
    int g = lane >> 4, wl = lane & 15;
    int base = wl * VPL;

    float xrv[VPL], av[VPL], acc[VPL];
#pragma unroll
    for (int v = 0; v < VPL; v++) {
        xrv[v] = xr[(size_t)wid * HC + base + v];
        av[v] = att[base + v];
        acc[v] = 0.0f;
    }
    float m = 0.0f, denom = 0.0f;

    int beg = rowptr[wid], end = rowptr[wid + 1];
    for (int chunk = beg; chunk < end; chunk += 64) {
        int cn = min(64, end - chunk);
        int my_src = (chunk + lane < end) ? srcs[chunk + lane] : 0;
        int iters = (cn + 3) >> 2;
        int slot = g;
        bool val = slot < cn;
        int src = __shfl(my_src, slot, 64);
        float xlv[VPL];
        {
            const float4* p = (const float4*)&xl[(size_t)src * HC + base];
            float4 a = p[0];
            xlv[0] = a.x; xlv[1] = a.y; xlv[2] = a.z; xlv[3] = a.w;
            if (VPL == 8) {
                float4 b_ = p[1];
                xlv[4] = b_.x; xlv[5] = b_.y; xlv[6] = b_.z; xlv[7] = b_.w;
            }
        }
        for (int j = 0; j < iters; j++) {
            int nslot = slot + 4;
            int nsrc = __shfl(my_src, nslot & 63, 64);
            float nxt[VPL];
            {
                const float4* p = (const float4*)&xl[(size_t)nsrc * HC + base];
                float4 a = p[0];
                nxt[0] = a.x; nxt[1] = a.y; nxt[2] = a.z; nxt[3] = a.w;
                if (VPL == 8) {
                    float4 b_ = p[1];
                    nxt[4] = b_.x; nxt[5] = b_.y; nxt[6] = b_.z; nxt[7] = b_.w;
                }
            }
            float s = 0.0f;
#pragma unroll
            for (int v = 0; v < VPL; v++) {
                float u = xlv[v] + xrv[v];
                u = (u >= 0.0f) ? u : SLOPE * u;
                s = fmaf(u, av[v], s);
            }
#pragma unroll
            for (int off = 1; off < RPH; off <<= 1) s += __shfl_xor(s, off, 64);
            if (!val) s = -1.0e30f;      // mask invalid slot -> p = 0
            if (s > m + 8.0f) {          // defer-max rescue (rarely taken)
                float sc = __expf(m - s);
                denom *= sc;
#pragma unroll
                for (int v = 0; v < VPL; v++) acc[v] *= sc;
                m = s;
            }
            float p = __expf(s - m);
            denom += p;
#pragma unroll
            for (int v = 0; v < VPL; v++) acc[v] = fmaf(p, xlv[v], acc[v]);
#pragma unroll
            for (int v = 0; v < VPL; v++) xlv[v] = nxt[v];
            val = nslot < cn;
            slot = nslot;
        }
    }
    // merge the 4 per-group softmax states (lanes wl, wl+16, wl+32, wl+48
    // hold the same features / same head)
#pragma unroll
    for (int step = 16; step <= 32; step <<= 1) {
        float om = __shfl_xor(m, step, 64);
        float od = __shfl_xor(denom, step, 64);
        float oa[VPL];
#pragma unroll
        for (int v = 0; v < VPL; v++) oa[v] = __shfl_xor(acc[v], step, 64);
        float mn = fmaxf(m, om);
        float sa = __expf(m - mn);
        float sb = __expf(om - mn);
        denom = denom * sa + od * sb;
#pragma unroll
        for (int v = 0; v < VPL; v++) acc[v] = acc[v] * sa + oa[v] * sb;
        m = mn;
    }
    if (g == 0) {
        float inv = 1.0f / denom;
        float4 o0;
        o0.x = acc[0] * inv + bias[base + 0];
        o0.y = acc[1] * inv + bias[base + 1];
        o0.z = acc[2] * inv + bias[base + 2];
        o0.w = acc[3] * inv + bias[base + 3];
        float4* po = (float4*)&out[(size_t)wid * HC + base];
        po[0] = o0;
        if (VPL == 8) {
            float4 o1;
            o1.x = acc[4] * inv + bias[base + 4];
            o1.y = acc[5] * inv + bias[base + 5];
            o1.z = acc[6] * inv + bias[base + 6];
            o1.w = acc[7] * inv + bias[base + 7];
            po[1] = o1;
        }
    }
}

// ---------------- fused classifier: relu(v@W1+b1)@W2+b2 ----------------------
__global__ __launch_bounds__(256) void classifier_kernel(
        const float* __restrict__ out2,
        const float* __restrict__ W1, const float* __restrict__ b1,
        const float* __restrict__ W2, const float* __restrict__ b2,
        float* __restrict__ y, int n) {
    __shared__ float sW1[64 * 32];
    __shared__ float sW2[32 * 64];
    __shared__ float sb1[32], sb2[64];
    int t = threadIdx.x;
    for (int i = t; i < 2048; i += 256) { sW1[i] = W1[i]; sW2[i] = W2[i]; }
    if (t < 32) sb1[t] = b1[t];
    if (t < 64) sb2[t] = b2[t];
    __syncthreads();
    int node = blockIdx.x * blockDim.x + t;
    if (node >= n) return;
    float v[64];
    const float4* src4 = (const float4*)&out2[(size_t)node * 64];
#pragma unroll
    for (int i = 0; i < 16; i++) {
        float4 f = src4[i];
        v[4 * i + 0] = f.x; v[4 * i + 1] = f.y; v[4 * i + 2] = f.z; v[4 * i + 3] = f.w;
    }
    float hid[32];
#pragma unroll
    for (int j = 0; j < 32; j++) {
        float s = sb1[j];
#pragma unroll
        for (int i = 0; i < 64; i++) s += v[i] * sW1[i * 32 + j];
        hid[j] = fmaxf(s, 0.0f);
    }
    float4* y4 = (float4*)&y[(size_t)node * 64];
#pragma unroll
    for (int o4 = 0; o4 < 16; o4++) {
        float4 o;
#pragma unroll
        for (int j = 0; j < 4; j++) {
            int o_ = o4 * 4 + j;
            float s = sb2[o_];
#pragma unroll
            for (int k = 0; k < 32; k++) s += hid[k] * sW2[k * 64 + o_];
            (&o.x)[j] = s;
        }
        y4[o4] = o;
    }
}

// =============================================================================
extern "C" void kernel_launch(void* const* d_in, const int* in_sizes, int n_in,
                              void* d_out, int out_size, void* d_ws, size_t ws_size,
                              hipStream_t stream) {
    const float* x        = (const float*)d_in[0];
    const int*   ei       = (const int*)d_in[1];
    const float* bn_in_g  = (const float*)d_in[2];
    const float* bn_in_b  = (const float*)d_in[3];
    const float* c0_Wl    = (const float*)d_in[4];
    const float* c0_bl    = (const float*)d_in[5];
    const float* c0_Wr    = (const float*)d_in[6];
    const float* c0_br    = (const float*)d_in[7];
    const float* c0_att   = (const float*)d_in[8];
    const float* c0_bias  = (const float*)d_in[9];
    const float* bn0_g    = (const float*)d_in[10];
    const float* bn0_b    = (const float*)d_in[11];
    const float* c1_Wl    = (const float*)d_in[12];
    const float* c1_bl    = (const float*)d_in[13];
    const float* c1_Wr    = (const float*)d_in[14];
    const float* c1_br    = (const float*)d_in[15];
    const float* c1_att   = (const float*)d_in[16];
    const float* c1_bias  = (const float*)d_in[17];
    const float* bn1_g    = (const float*)d_in[18];
    const float* bn1_b    = (const float*)d_in[19];
    const float* c2_Wl    = (const float*)d_in[20];
    const float* c2_bl    = (const float*)d_in[21];
    const float* c2_Wr    = (const float*)d_in[22];
    const float* c2_br    = (const float*)d_in[23];
    const float* c2_att   = (const float*)d_in[24];
    const float* c2_bias  = (const float*)d_in[25];
    const float* cls_w1   = (const float*)d_in[26];
    const float* cls_b1   = (const float*)d_in[27];
    const float* cls_w2   = (const float*)d_in[28];
    const float* cls_b2   = (const float*)d_in[29];

    const int N = in_sizes[0] / 128;
    const int E = in_sizes[1] / 2;
    const int Et = E + N;

    float* ws = (float*)d_ws;
    size_t off = 0;
    auto alloc = [&](size_t nf) { float* p = ws + off; off += nf; return p; };
    float* hA     = alloc((size_t)N * 128);
    float* xlb    = alloc((size_t)N * 128);
    float* xrb    = alloc((size_t)N * 128);
    float* outb   = alloc((size_t)N * 128);
    // deg + 3 stats buffers contiguous -> single memset
    int* deg      = (int*)alloc(N);
    float* statsI = alloc(256);
    float* stats0 = alloc(256);
    float* stats1 = alloc(256);
    int* rowptr   = (int*)alloc(N + 1);
    int* cursor   = (int*)alloc(N);
    int* srcs     = (int*)alloc(Et);
    int* bsum     = (int*)alloc(256);

    const int et_blocks = (Et + 255) / 256;
    const int elem128   = (N * 32 + 255) / 256;
    const int nb        = (N + 255) / 256;
    const int gw        = (N + 3) / 4;                // gather: 1 wave/node
    dim3 gemm_grid_128(2, (N + 63) / 64);
    dim3 gemm_grid_64(1, (N + 63) / 64);

    // ---- one memset zeroes deg + all 3 stats buffers ----
    hipMemsetAsync(deg, 0, ((size_t)N + 768) * sizeof(int), stream);

    // ---- CSR build (once; graph shared by all layers) ----
    degree_kernel<<<et_blocks, 256, 0, stream>>>(ei, E, Et, deg);
    blocksum_kernel<<<nb, 256, 0, stream>>>(deg, N, bsum);
    scanb_kernel<<<1, 256, 0, stream>>>(bsum, nb);
    rowptr_kernel<<<nb, 256, 0, stream>>>(deg, bsum, N, rowptr, cursor);
    scatter_kernel<<<et_blocks, 256, 0, stream>>>(ei, E, Et, cursor, srcs);

    // ---- input BN ----
    col_stats_kernel<<<512, 128, 0, stream>>>(x, statsI, N, 128);
    bn_apply_kernel<<<elem128, 256, 0, stream>>>((const float4*)x, statsI, bn_in_g, bn_in_b,
                                                 (float4*)hA, N, 128);

    float* h = hA;

    // ================= layer 0 =================
    gemm_mfma_kernel<<<gemm_grid_128, 256, 0, stream>>>(h, c0_Wl, c0_bl, xlb, N, 128);
    gemm_mfma_kernel<<<gemm_grid_128, 256, 0, stream>>>(h, c0_Wr, c0_br, xrb, N, 128);
    gat_gather_kernel<4, 32><<<gw, 256, 0, stream>>>(xlb, xrb, c0_att, c0_bias, rowptr, srcs, outb, N);
    col_stats_kernel<<<512, 128, 0, stream>>>(outb, stats0, N, 128);
    bn_elu_res_kernel<<<elem128, 256, 0, stream>>>((const float4*)outb, stats0, bn0_g, bn0_b,
                                                   (const float4*)h, (float4*)xrb, N, 128);
    h = xrb;  // hA now free

    // ================= layer 1 =================
    gemm_mfma_kernel<<<gemm_grid_128, 256, 0, stream>>>(h, c1_Wl, c1_bl, xlb, N, 128);
    gemm_mfma_kernel<<<gemm_grid_128, 256, 0, stream>>>(h, c1_Wr, c1_br, hA, N, 128);
    gat_gather_kernel<4, 32><<<gw, 256, 0, stream>>>(xlb, hA, c1_att, c1_bias, rowptr, srcs, outb, N);
    col_stats_kernel<<<512, 128, 0, stream>>>(outb, stats1, N, 128);
    bn_elu_res_kernel<<<elem128, 256, 0, stream>>>((const float4*)outb, stats1, bn1_g, bn1_b,
                                                   (const float4*)h, (float4*)hA, N, 128);
    h = hA;

    // ================= layer 2 (H=1, C=64) =================
    gemm_mfma_kernel<<<gemm_grid_64, 256, 0, stream>>>(h, c2_Wl, c2_bl, xlb, N, 64);
    gemm_mfma_kernel<<<gemm_grid_64, 256, 0, stream>>>(h, c2_Wr, c2_br, xrb, N, 64);
    gat_gather_kernel<1, 64><<<gw, 256, 0, stream>>>(xlb, xrb, c2_att, c2_bias, rowptr, srcs, outb, N);

    // ---- classifier (conv2 bias already fused into gather) ----
    classifier_kernel<<<(N + 255) / 256, 256, 0, stream>>>(outb, cls_w1, cls_b1,
                                                           cls_w2, cls_b2, (float*)d_out, N);
}